// Round 1
// baseline (1872.370 us; speedup 1.0000x reference)
//
#include <hip/hip_runtime.h>
#include <hip/hip_bf16.h>

// GCN forward: x1 = relu(agg(F) @ W1 + b1); x2 = relu(agg(x1) @ W2 + b2);
// out = relu(x2 @ W3 + b3).   agg is linear => agg(X) @ W == agg(X @ W),
// so we GEMM first, then aggregate (smaller aggregation traffic, dense GEMM A).

#define N_NODES 20000
#define N_EDGES 200000
#define D_IN    1433
#define D_H1    1000
#define D_H2    500
#define D_OUT   7

// ---------------------------------------------------------------- CSR build
__global__ __launch_bounds__(256) void count_deg(const int* __restrict__ dst,
                                                 int* __restrict__ offs) {
    int e = blockIdx.x * 256 + threadIdx.x;
    if (e < N_EDGES) atomicAdd(&offs[dst[e] + 1], 1);
}

// single-block inclusive scan over n ints (n ~ 20001)
__global__ __launch_bounds__(1024) void scan_inclusive(int* __restrict__ data, int n) {
    __shared__ int buf[1024];
    __shared__ int carry;
    int t = threadIdx.x;
    if (t == 0) carry = 0;
    __syncthreads();
    for (int base = 0; base < n; base += 1024) {
        int i = base + t;
        int v = (i < n) ? data[i] : 0;
        buf[t] = v;
        __syncthreads();
        #pragma unroll
        for (int s = 1; s < 1024; s <<= 1) {
            int u = (t >= s) ? buf[t - s] : 0;
            __syncthreads();
            buf[t] += u;
            __syncthreads();
        }
        int c = carry;
        if (i < n) data[i] = buf[t] + c;
        __syncthreads();
        if (t == 1023) carry = c + buf[1023];
        __syncthreads();
    }
}

__global__ __launch_bounds__(256) void fill_csr(const int* __restrict__ src,
                                                const int* __restrict__ dst,
                                                int* __restrict__ cursor,
                                                int* __restrict__ srcs) {
    int e = blockIdx.x * 256 + threadIdx.x;
    if (e < N_EDGES) {
        int pos = atomicAdd(&cursor[dst[e]], 1);
        srcs[pos] = src[e];
    }
}

// ------------------------------------------------- per-node gather aggregation
// A[i][:] = sum_{j in CSR(i)} H[j][:]   (no atomics; fully writes A)
template <int D>
__global__ __launch_bounds__(256) void agg_csr(const float* __restrict__ H,
                                               const int* __restrict__ offs,
                                               const int* __restrict__ srcs,
                                               float* __restrict__ A) {
    __shared__ int sl[256];
    int i = blockIdx.x;
    int beg = offs[i], end = offs[i + 1];
    int t = threadIdx.x;
    float s[4] = {0.f, 0.f, 0.f, 0.f};
    for (int base = beg; base < end; base += 256) {
        int n = min(256, end - base);
        __syncthreads();
        if (t < n) sl[t] = srcs[base + t];
        __syncthreads();
        for (int e = 0; e < n; ++e) {
            const float* row = H + (size_t)sl[e] * D;
            #pragma unroll
            for (int u = 0; u < 4; ++u) {
                int d = t + 256 * u;
                if (d < D) s[u] += row[d];
            }
        }
    }
    #pragma unroll
    for (int u = 0; u < 4; ++u) {
        int d = t + 256 * u;
        if (d < D) A[(size_t)i * D + d] = s[u];
    }
}

// ------------------------------------------------------------- fp32 tiled GEMM
// C[M,N] = op(A)[M,K] @ B[K,N];  op(A) = relu(A + biasA[k]) if FUSE_A.
// 64x64 tile, BK=16, 256 threads, 4x4 per thread.
template <bool FUSE_A>
__global__ __launch_bounds__(256) void gemm_tiled(const float* __restrict__ A,
                                                  const float* __restrict__ B,
                                                  const float* __restrict__ biasA,
                                                  float* __restrict__ C,
                                                  int M, int K, int N) {
    __shared__ float As[16][68];  // k-major; 68 floats/row keeps rows 16B-aligned
    __shared__ float Bs[16][64];
    int t  = threadIdx.x;
    int tx = t & 15;   // n-subtile
    int ty = t >> 4;   // m-subtile
    int m0 = blockIdx.x * 64;
    int n0 = blockIdx.y * 64;

    int la_k = t & 15;  // A staging: k within tile
    int la_m = t >> 4;  // A staging: m rows la_m + 16*i
    int lb_n = t & 63;  // B staging: n within tile
    int lb_k = t >> 6;  // B staging: k rows lb_k + 4*i

    float acc[4][4] = {};

    for (int k0 = 0; k0 < K; k0 += 16) {
        #pragma unroll
        for (int i = 0; i < 4; ++i) {
            int m = m0 + la_m + 16 * i;
            int k = k0 + la_k;
            float v = 0.f;
            if (m < M && k < K) {
                v = A[(size_t)m * K + k];
                if (FUSE_A) v = fmaxf(v + biasA[k], 0.f);
            }
            As[la_k][la_m + 16 * i] = v;
        }
        #pragma unroll
        for (int i = 0; i < 4; ++i) {
            int k = k0 + lb_k + 4 * i;
            int n = n0 + lb_n;
            float v = 0.f;
            if (k < K && n < N) v = B[(size_t)k * N + n];
            Bs[lb_k + 4 * i][lb_n] = v;
        }
        __syncthreads();
        #pragma unroll
        for (int kk = 0; kk < 16; ++kk) {
            float a0 = As[kk][ty * 4 + 0];
            float a1 = As[kk][ty * 4 + 1];
            float a2 = As[kk][ty * 4 + 2];
            float a3 = As[kk][ty * 4 + 3];
            float b0 = Bs[kk][tx * 4 + 0];
            float b1 = Bs[kk][tx * 4 + 1];
            float b2 = Bs[kk][tx * 4 + 2];
            float b3 = Bs[kk][tx * 4 + 3];
            acc[0][0] += a0 * b0; acc[0][1] += a0 * b1; acc[0][2] += a0 * b2; acc[0][3] += a0 * b3;
            acc[1][0] += a1 * b0; acc[1][1] += a1 * b1; acc[1][2] += a1 * b2; acc[1][3] += a1 * b3;
            acc[2][0] += a2 * b0; acc[2][1] += a2 * b1; acc[2][2] += a2 * b2; acc[2][3] += a2 * b3;
            acc[3][0] += a3 * b0; acc[3][1] += a3 * b1; acc[3][2] += a3 * b2; acc[3][3] += a3 * b3;
        }
        __syncthreads();
    }

    #pragma unroll
    for (int i = 0; i < 4; ++i) {
        int m = m0 + ty * 4 + i;
        if (m >= M) continue;
        #pragma unroll
        for (int j = 0; j < 4; ++j) {
            int n = n0 + tx * 4 + j;
            if (n < N) C[(size_t)m * N + n] = acc[i][j];
        }
    }
}

// ------------------------------------------------------- layer 3 (N = 7, tiny)
// out[i][:] = relu( relu(A2[i][:] + b2) @ W3 + b3 ) ; one wave per node
__global__ __launch_bounds__(256) void out_layer(const float* __restrict__ A2,
                                                 const float* __restrict__ b2,
                                                 const float* __restrict__ W3,
                                                 const float* __restrict__ b3,
                                                 float* __restrict__ out) {
    int wave = threadIdx.x >> 6;
    int lane = threadIdx.x & 63;
    int node = blockIdx.x * 4 + wave;
    if (node >= N_NODES) return;
    const float* row = A2 + (size_t)node * D_H2;
    float acc[D_OUT] = {};
    for (int k = lane; k < D_H2; k += 64) {
        float x = fmaxf(row[k] + b2[k], 0.f);
        #pragma unroll
        for (int j = 0; j < D_OUT; ++j) acc[j] += x * W3[k * D_OUT + j];
    }
    #pragma unroll
    for (int j = 0; j < D_OUT; ++j)
        #pragma unroll
        for (int off = 32; off; off >>= 1) acc[j] += __shfl_down(acc[j], off);
    if (lane == 0) {
        #pragma unroll
        for (int j = 0; j < D_OUT; ++j)
            out[(size_t)node * D_OUT + j] = fmaxf(acc[j] + b3[j], 0.f);
    }
}

// ---------------------------------------------------------------------- launch
extern "C" void kernel_launch(void* const* d_in, const int* in_sizes, int n_in,
                              void* d_out, int out_size, void* d_ws, size_t ws_size,
                              hipStream_t stream) {
    const float* features = (const float*)d_in[0];
    const int*   src      = (const int*)d_in[1];
    const int*   dst      = (const int*)d_in[2];
    const float* W1       = (const float*)d_in[3];
    const float* b1       = (const float*)d_in[4];
    const float* W2       = (const float*)d_in[5];
    const float* b2       = (const float*)d_in[6];
    const float* W3       = (const float*)d_in[7];
    const float* b3       = (const float*)d_in[8];
    float* out = (float*)d_out;

    // workspace layout (bytes)
    char* ws = (char*)d_ws;
    const size_t BUF0 = 0;                      // H1 [20000x1000] then H2 [20000x500]
    const size_t BUF1 = 80000000;               // A1 [20000x1000] then A2 [20000x500]
    const size_t OFFS = 160000000;              // offs [20001] int
    const size_t CURS = OFFS + 80128;           // cursor [20000] int
    const size_t SRCS = CURS + 80128;           // sorted src [200000] int
    float* H1 = (float*)(ws + BUF0);
    float* A1 = (float*)(ws + BUF1);
    float* H2 = (float*)(ws + BUF0);
    float* A2 = (float*)(ws + BUF1);
    int* offs   = (int*)(ws + OFFS);
    int* cursor = (int*)(ws + CURS);
    int* srcs   = (int*)(ws + SRCS);

    // ---- CSR build (per call: d_ws is re-poisoned before every launch)
    hipMemsetAsync(offs, 0, (N_NODES + 1) * sizeof(int), stream);
    count_deg<<<(N_EDGES + 255) / 256, 256, 0, stream>>>(dst, offs);
    scan_inclusive<<<1, 1024, 0, stream>>>(offs, N_NODES + 1);
    hipMemcpyAsync(cursor, offs, N_NODES * sizeof(int), hipMemcpyDeviceToDevice, stream);
    fill_csr<<<(N_EDGES + 255) / 256, 256, 0, stream>>>(src, dst, cursor, srcs);

    // ---- layer 1: H1 = F @ W1 ; A1 = agg(H1)
    gemm_tiled<false><<<dim3(313, 16), 256, 0, stream>>>(features, W1, nullptr, H1,
                                                         N_NODES, D_IN, D_H1);
    agg_csr<D_H1><<<N_NODES, 256, 0, stream>>>(H1, offs, srcs, A1);

    // ---- layer 2: H2 = relu(A1 + b1) @ W2 ; A2 = agg(H2)
    gemm_tiled<true><<<dim3(313, 8), 256, 0, stream>>>(A1, W2, b1, H2,
                                                       N_NODES, D_H1, D_H2);
    agg_csr<D_H2><<<N_NODES, 256, 0, stream>>>(H2, offs, srcs, A2);

    // ---- layer 3: out = relu(relu(A2 + b2) @ W3 + b3)
    out_layer<<<(N_NODES + 3) / 4, 256, 0, stream>>>(A2, b2, W3, b3, out);
}

// Round 2
// 634.947 us; speedup vs baseline: 2.9489x; 2.9489x over previous
//
#include <hip/hip_runtime.h>
#include <hip/hip_bf16.h>

// GCN forward, bf16-MFMA edition.
//   H1 = F @ W1            (bf16 MFMA, fp32 acc)
//   X1 = relu(agg(H1)+b1)  (fused agg epilogue, emits padded bf16)
//   H2 = X1 @ W2           (bf16 MFMA)
//   X2 = relu(agg(H2)+b2)  (fp32)
//   out = relu(X2 @ W3 + b3)
// agg is linear => agg(X)@W == agg(X@W); relu applied after the add, so the
// commute is exact (modulo fp order).

#define N_NODES 20000
#define N_EDGES 200000
#define D_IN    1433
#define D_H1    1000
#define D_H2    500
#define D_OUT   7

#define MPAD    20096        // 157 * 128
#define K1PAD   1440         // D_IN  padded to mult of 32
#define N1PAD   1024         // D_H1  padded to 128
#define K2PAD   1024         // D_H1  padded to 32 (and 128 for B rows)
#define N2PAD   512          // D_H2  padded to 128

typedef __attribute__((ext_vector_type(8))) short short8;
typedef __attribute__((ext_vector_type(4))) float f32x4;

__device__ __forceinline__ unsigned short bf16_rne(float x) {
    unsigned int u = __float_as_uint(x);
    u = (u + 0x7FFFu + ((u >> 16) & 1u)) >> 16;
    return (unsigned short)u;
}

__device__ __forceinline__ void gl_lds16(const unsigned short* g, unsigned short* lds) {
    __builtin_amdgcn_global_load_lds(
        (const __attribute__((address_space(1))) unsigned int*)g,
        (__attribute__((address_space(3))) unsigned int*)lds, 16, 0, 0);
}

// ---------------------------------------------------------------- CSR build
__global__ __launch_bounds__(256) void count_deg(const int* __restrict__ dst,
                                                 int* __restrict__ offs) {
    int e = blockIdx.x * 256 + threadIdx.x;
    if (e < N_EDGES) atomicAdd(&offs[dst[e] + 1], 1);
}

__global__ __launch_bounds__(1024) void scan_inclusive(int* __restrict__ data, int n) {
    __shared__ int buf[1024];
    __shared__ int carry;
    int t = threadIdx.x;
    if (t == 0) carry = 0;
    __syncthreads();
    for (int base = 0; base < n; base += 1024) {
        int i = base + t;
        int v = (i < n) ? data[i] : 0;
        buf[t] = v;
        __syncthreads();
        #pragma unroll
        for (int s = 1; s < 1024; s <<= 1) {
            int u = (t >= s) ? buf[t - s] : 0;
            __syncthreads();
            buf[t] += u;
            __syncthreads();
        }
        int c = carry;
        if (i < n) data[i] = buf[t] + c;
        __syncthreads();
        if (t == 1023) carry = c + buf[1023];
        __syncthreads();
    }
}

__global__ __launch_bounds__(256) void fill_csr(const int* __restrict__ src,
                                                const int* __restrict__ dst,
                                                int* __restrict__ cursor,
                                                int* __restrict__ srcs) {
    int e = blockIdx.x * 256 + threadIdx.x;
    if (e < N_EDGES) {
        int pos = atomicAdd(&cursor[dst[e]], 1);
        srcs[pos] = src[e];
    }
}

// --------------------------------------------------------------- input casts
// features fp32 [20000][1433] -> bf16 [MPAD][K1PAD], pads zeroed, packed u32 writes
__global__ __launch_bounds__(256) void cast_features(const float* __restrict__ F,
                                                     unsigned int* __restrict__ out) {
    int row = blockIdx.x;
    int t = threadIdx.x;
    const float* fr = F + (size_t)row * D_IN;
    bool live = row < N_NODES;
    for (int kk = t; kk < K1PAD / 2; kk += 256) {
        int k0 = kk * 2;
        float a = (live && k0     < D_IN) ? fr[k0]     : 0.f;
        float b = (live && k0 + 1 < D_IN) ? fr[k0 + 1] : 0.f;
        out[(size_t)row * (K1PAD / 2) + kk] =
            (unsigned int)bf16_rne(a) | ((unsigned int)bf16_rne(b) << 16);
    }
}

// W [SR][SC] fp32 -> WT [DR][DC] bf16 with WT[c][r]=W[r][c], pads zeroed.
template <int SR, int SC, int DR, int DC>
__global__ __launch_bounds__(256) void transpose_cast_pad(const float* __restrict__ src,
                                                          unsigned short* __restrict__ dst) {
    __shared__ float tile[32][33];
    int c0 = blockIdx.x * 32;  // src col block == dst row block
    int r0 = blockIdx.y * 32;  // src row block == dst col block
    int tx = threadIdx.x & 31, ty = threadIdx.x >> 5;  // ty in 0..7
    #pragma unroll
    for (int p = 0; p < 4; ++p) {
        int r = r0 + ty + p * 8, c = c0 + tx;
        tile[ty + p * 8][tx] = (r < SR && c < SC) ? src[(size_t)r * SC + c] : 0.f;
    }
    __syncthreads();
    #pragma unroll
    for (int p = 0; p < 4; ++p) {
        int dr = c0 + ty + p * 8;  // dst row (src col)
        int dc = r0 + tx;          // dst col (src row)
        if (dr < DR && dc < DC) dst[(size_t)dr * DC + dc] = bf16_rne(tile[tx][ty + p * 8]);
    }
}

// -------------------------------------------------------------- bf16 MFMA GEMM
// C[M,N] = A[MPAD,KPAD](bf16) @ B^T rows[NPAD,KPAD](bf16), fp32 out stride N.
// 128x128 tile, BK=32, 256 thr = 4 waves, wave = 64x64 (4x4 16x16x32 MFMAs).
template <int KPAD>
__global__ __launch_bounds__(256) void gemm_mfma(const unsigned short* __restrict__ A,
                                                 const unsigned short* __restrict__ B,
                                                 float* __restrict__ C,
                                                 int M, int N) {
    __shared__ __align__(16) unsigned short sA[128 * 32];
    __shared__ __align__(16) unsigned short sB[128 * 32];
    const int t = threadIdx.x;
    const int w = t >> 6, lane = t & 63;
    const int m0 = blockIdx.x * 128, n0 = blockIdx.y * 128;
    const int wm = (w >> 1) * 64, wn = (w & 1) * 64;

    // staging: per wave, 64 lanes x 16B = 16 rows of 32 bf16; 2 chunks cover 128 rows
    const int srow = lane >> 2;          // row within wave's 16-row group
    const int skc  = (lane & 3) * 8;     // k element offset 0/8/16/24

    const int mrow = lane & 15, quad = lane >> 4;

    f32x4 acc[4][4] = {};

    for (int k0 = 0; k0 < KPAD; k0 += 32) {
        #pragma unroll
        for (int c = 0; c < 2; ++c) {
            int rbase = c * 64 + w * 16;
            gl_lds16(A + (size_t)(m0 + rbase + srow) * KPAD + k0 + skc, &sA[rbase * 32]);
            gl_lds16(B + (size_t)(n0 + rbase + srow) * KPAD + k0 + skc, &sB[rbase * 32]);
        }
        __syncthreads();  // compiler emits s_waitcnt vmcnt(0) before the barrier

        short8 af[4], bf[4];
        #pragma unroll
        for (int mt = 0; mt < 4; ++mt)
            af[mt] = *(const short8*)&sA[(wm + mt * 16 + mrow) * 32 + quad * 8];
        #pragma unroll
        for (int nt = 0; nt < 4; ++nt)
            bf[nt] = *(const short8*)&sB[(wn + nt * 16 + mrow) * 32 + quad * 8];
        #pragma unroll
        for (int mt = 0; mt < 4; ++mt)
            #pragma unroll
            for (int nt = 0; nt < 4; ++nt)
                acc[mt][nt] = __builtin_amdgcn_mfma_f32_16x16x32_bf16(
                    af[mt], bf[nt], acc[mt][nt], 0, 0, 0);
        __syncthreads();
    }

    // C/D layout: col = lane&15, row = quad*4 + reg  [m89-verified]
    #pragma unroll
    for (int mt = 0; mt < 4; ++mt) {
        int m = m0 + wm + mt * 16 + quad * 4;
        #pragma unroll
        for (int nt = 0; nt < 4; ++nt) {
            int n = n0 + wn + nt * 16 + mrow;
            if (n >= N) continue;
            #pragma unroll
            for (int r = 0; r < 4; ++r)
                if (m + r < M) C[(size_t)(m + r) * N + n] = acc[mt][nt][r];
        }
    }
}

// ---------------------------------------------- fused aggregation + bias + relu
// out_i = relu(sum_{j in CSR(i)} H[j] + bias); BF16OUT writes padded bf16 rows.
template <int D, bool BF16OUT, int OSTRIDE>
__global__ __launch_bounds__(256) void agg_fuse(const float* __restrict__ H,
                                                const int* __restrict__ offs,
                                                const int* __restrict__ srcs,
                                                const float* __restrict__ bias,
                                                void* __restrict__ outp) {
    __shared__ int sl[256];
    const int i = blockIdx.x, t = threadIdx.x;
    const int beg = offs[i], end = offs[i + 1];
    constexpr int D4 = D / 4;
    float4 s = {0.f, 0.f, 0.f, 0.f};
    for (int base = beg; base < end; base += 256) {
        int n = min(256, end - base);
        __syncthreads();
        if (t < n) sl[t] = srcs[base + t];
        __syncthreads();
        for (int e = 0; e < n; ++e) {
            if (t < D4) {
                float4 v = ((const float4*)(H + (size_t)sl[e] * D))[t];
                s.x += v.x; s.y += v.y; s.z += v.z; s.w += v.w;
            }
        }
    }
    if (BF16OUT) {
        ushort4 o = {0, 0, 0, 0};
        if (t < D4) {
            float4 b = ((const float4*)bias)[t];
            o.x = bf16_rne(fmaxf(s.x + b.x, 0.f));
            o.y = bf16_rne(fmaxf(s.y + b.y, 0.f));
            o.z = bf16_rne(fmaxf(s.z + b.z, 0.f));
            o.w = bf16_rne(fmaxf(s.w + b.w, 0.f));
        }
        if (t < OSTRIDE / 4)
            ((ushort4*)((unsigned short*)outp + (size_t)i * OSTRIDE))[t] = o;
    } else {
        if (t < D4) {
            float4 b = ((const float4*)bias)[t];
            float4 o;
            o.x = fmaxf(s.x + b.x, 0.f); o.y = fmaxf(s.y + b.y, 0.f);
            o.z = fmaxf(s.z + b.z, 0.f); o.w = fmaxf(s.w + b.w, 0.f);
            ((float4*)((float*)outp + (size_t)i * D))[t] = o;
        }
    }
}

// ------------------------------------------------------- layer 3 (N = 7, tiny)
// out[i][:] = relu(X2[i][:] @ W3 + b3); X2 already has bias+relu applied.
__global__ __launch_bounds__(256) void out_layer(const float* __restrict__ X2,
                                                 const float* __restrict__ W3,
                                                 const float* __restrict__ b3,
                                                 float* __restrict__ out) {
    int wave = threadIdx.x >> 6;
    int lane = threadIdx.x & 63;
    int node = blockIdx.x * 4 + wave;
    if (node >= N_NODES) return;
    const float* row = X2 + (size_t)node * D_H2;
    float acc[D_OUT] = {};
    for (int k = lane; k < D_H2; k += 64) {
        float x = row[k];
        #pragma unroll
        for (int j = 0; j < D_OUT; ++j) acc[j] += x * W3[k * D_OUT + j];
    }
    #pragma unroll
    for (int j = 0; j < D_OUT; ++j)
        #pragma unroll
        for (int off = 32; off; off >>= 1) acc[j] += __shfl_down(acc[j], off);
    if (lane == 0) {
        #pragma unroll
        for (int j = 0; j < D_OUT; ++j)
            out[(size_t)node * D_OUT + j] = fmaxf(acc[j] + b3[j], 0.f);
    }
}

// ---------------------------------------------------------------------- launch
extern "C" void kernel_launch(void* const* d_in, const int* in_sizes, int n_in,
                              void* d_out, int out_size, void* d_ws, size_t ws_size,
                              hipStream_t stream) {
    const float* features = (const float*)d_in[0];
    const int*   src      = (const int*)d_in[1];
    const int*   dst      = (const int*)d_in[2];
    const float* W1       = (const float*)d_in[3];
    const float* b1       = (const float*)d_in[4];
    const float* W2       = (const float*)d_in[5];
    const float* b2       = (const float*)d_in[6];
    const float* W3       = (const float*)d_in[7];
    const float* b3       = (const float*)d_in[8];
    float* out = (float*)d_out;

    char* ws = (char*)d_ws;
    // layout (bytes); X1bf overlays Fbf (GEMM1 finished before agg1 writes),
    // H2 + X2 overlay H1 (H1 dead after agg1).
    unsigned short* Fbf  = (unsigned short*)(ws + 0);            // [MPAD][K1PAD] bf16 = 57,876,480
    unsigned short* X1bf = (unsigned short*)(ws + 0);            // [MPAD][K2PAD] bf16 = 41,156,608
    float* H1 = (float*)(ws + 57876480);                         // [20000][1000] f32 = 80,000,000
    float* H2 = (float*)(ws + 57876480);                         // [20000][500]  f32 = 40,000,000
    float* X2 = (float*)(ws + 97876480);                         // [20000][500]  f32 = 40,000,000
    unsigned short* W1T = (unsigned short*)(ws + 137876480);     // [N1PAD][K1PAD] = 2,949,120
    unsigned short* W2T = (unsigned short*)(ws + 140825600);     // [N2PAD][K2PAD] = 1,048,576
    int* offs   = (int*)(ws + 141874176);                        // 20001 ints
    int* cursor = (int*)(ws + 141954304);
    int* srcs   = (int*)(ws + 142034432);                        // 200000 ints

    // ---- CSR build
    hipMemsetAsync(offs, 0, (N_NODES + 1) * sizeof(int), stream);
    count_deg<<<(N_EDGES + 255) / 256, 256, 0, stream>>>(dst, offs);
    scan_inclusive<<<1, 1024, 0, stream>>>(offs, N_NODES + 1);
    hipMemcpyAsync(cursor, offs, N_NODES * sizeof(int), hipMemcpyDeviceToDevice, stream);
    fill_csr<<<(N_EDGES + 255) / 256, 256, 0, stream>>>(src, dst, cursor, srcs);

    // ---- casts
    cast_features<<<MPAD, 256, 0, stream>>>(features, (unsigned int*)Fbf);
    transpose_cast_pad<D_IN, D_H1, N1PAD, K1PAD>
        <<<dim3(N1PAD / 32, K1PAD / 32), 256, 0, stream>>>(W1, W1T);
    transpose_cast_pad<D_H1, D_H2, N2PAD, K2PAD>
        <<<dim3(N2PAD / 32, K2PAD / 32), 256, 0, stream>>>(W2, W2T);

    // ---- layer 1
    gemm_mfma<K1PAD><<<dim3(157, 8), 256, 0, stream>>>(Fbf, W1T, H1, N_NODES, D_H1);
    // zero X1bf pad rows (20000..20095) before GEMM2 stages them
    hipMemsetAsync(ws + (size_t)N_NODES * K2PAD * 2, 0, (size_t)(MPAD - N_NODES) * K2PAD * 2, stream);
    agg_fuse<D_H1, true, K2PAD><<<N_NODES, 256, 0, stream>>>(H1, offs, srcs, b1, X1bf);

    // ---- layer 2
    gemm_mfma<K2PAD><<<dim3(157, 4), 256, 0, stream>>>(X1bf, W2T, H2, N_NODES, D_H2);
    agg_fuse<D_H2, false, D_H2><<<N_NODES, 256, 0, stream>>>(H2, offs, srcs, b2, X2);

    // ---- layer 3
    out_layer<<<(N_NODES + 3) / 4, 256, 0, stream>>>(X2, W3, b3, out);
}

// Round 3
// 494.088 us; speedup vs baseline: 3.7895x; 1.2851x over previous
//
#include <hip/hip_runtime.h>
#include <hip/hip_bf16.h>

// GCN forward, bf16-MFMA + bf16 intermediates.
//   H1 = F @ W1                  (bf16 MFMA, bf16 out, stride 1008)
//   X1 = relu(agg(H1)+b1)        (bf16 gather-agg, bf16 out padded to 1024)
//   H2 = X1 @ W2                 (bf16 MFMA, bf16 out, stride 504)
//   out = relu(relu(agg(H2)+b2) @ W3 + b3)   (fused agg+layer3)
// agg is linear => agg(X)@W == agg(X@W).

#define N_NODES 20000
#define N_EDGES 200000
#define D_IN    1433
#define D_H1    1000
#define D_H2    500
#define D_OUT   7

#define MPAD    20096        // 157 * 128
#define K1PAD   1440         // D_IN padded to mult of 32
#define N1PAD   1024
#define K2PAD   1024
#define N2PAD   512
#define H1STR   1008         // bf16 row stride (2016 B, 16B-aligned)
#define H2STR   504          // bf16 row stride (1008 B, 8B-aligned)

typedef __attribute__((ext_vector_type(8))) short short8;
typedef __attribute__((ext_vector_type(8))) unsigned short ushort8_t;
typedef __attribute__((ext_vector_type(4))) float f32x4;

__device__ __forceinline__ unsigned short bf16_rne(float x) {
    unsigned int u = __float_as_uint(x);
    u = (u + 0x7FFFu + ((u >> 16) & 1u)) >> 16;
    return (unsigned short)u;
}
__device__ __forceinline__ float bf16_up(unsigned short h) {
    return __uint_as_float((unsigned int)h << 16);
}

__device__ __forceinline__ void gl_lds16(const unsigned short* g, unsigned short* lds) {
    __builtin_amdgcn_global_load_lds(
        (const __attribute__((address_space(1))) unsigned int*)g,
        (__attribute__((address_space(3))) unsigned int*)lds, 16, 0, 0);
}

// ---------------------------------------------------------------- CSR build
__global__ __launch_bounds__(256) void count_deg(const int* __restrict__ dst,
                                                 int* __restrict__ offs) {
    int e = blockIdx.x * 256 + threadIdx.x;
    if (e < N_EDGES) atomicAdd(&offs[dst[e] + 1], 1);
}

__global__ __launch_bounds__(1024) void scan_inclusive(int* __restrict__ data, int n) {
    __shared__ int buf[1024];
    __shared__ int carry;
    int t = threadIdx.x;
    if (t == 0) carry = 0;
    __syncthreads();
    for (int base = 0; base < n; base += 1024) {
        int i = base + t;
        int v = (i < n) ? data[i] : 0;
        buf[t] = v;
        __syncthreads();
        #pragma unroll
        for (int s = 1; s < 1024; s <<= 1) {
            int u = (t >= s) ? buf[t - s] : 0;
            __syncthreads();
            buf[t] += u;
            __syncthreads();
        }
        int c = carry;
        if (i < n) data[i] = buf[t] + c;
        __syncthreads();
        if (t == 1023) carry = c + buf[1023];
        __syncthreads();
    }
}

__global__ __launch_bounds__(256) void fill_csr(const int* __restrict__ src,
                                                const int* __restrict__ dst,
                                                int* __restrict__ cursor,
                                                int* __restrict__ srcs) {
    int e = blockIdx.x * 256 + threadIdx.x;
    if (e < N_EDGES) {
        int pos = atomicAdd(&cursor[dst[e]], 1);
        srcs[pos] = src[e];
    }
}

// --------------------------------------------------------------- input casts
__global__ __launch_bounds__(256) void cast_features(const float* __restrict__ F,
                                                     unsigned int* __restrict__ out) {
    int row = blockIdx.x;
    int t = threadIdx.x;
    const float* fr = F + (size_t)row * D_IN;
    bool live = row < N_NODES;
    for (int kk = t; kk < K1PAD / 2; kk += 256) {
        int k0 = kk * 2;
        float a = (live && k0     < D_IN) ? fr[k0]     : 0.f;
        float b = (live && k0 + 1 < D_IN) ? fr[k0 + 1] : 0.f;
        out[(size_t)row * (K1PAD / 2) + kk] =
            (unsigned int)bf16_rne(a) | ((unsigned int)bf16_rne(b) << 16);
    }
}

// W [SR][SC] fp32 -> WT [DR][DC] bf16 with WT[c][r]=W[r][c], pads zeroed.
template <int SR, int SC, int DR, int DC>
__global__ __launch_bounds__(256) void transpose_cast_pad(const float* __restrict__ src,
                                                          unsigned short* __restrict__ dst) {
    __shared__ float tile[32][33];
    int c0 = blockIdx.x * 32;
    int r0 = blockIdx.y * 32;
    int tx = threadIdx.x & 31, ty = threadIdx.x >> 5;
    #pragma unroll
    for (int p = 0; p < 4; ++p) {
        int r = r0 + ty + p * 8, c = c0 + tx;
        tile[ty + p * 8][tx] = (r < SR && c < SC) ? src[(size_t)r * SC + c] : 0.f;
    }
    __syncthreads();
    #pragma unroll
    for (int p = 0; p < 4; ++p) {
        int dr = c0 + ty + p * 8;
        int dc = r0 + tx;
        if (dr < DR && dc < DC) dst[(size_t)dr * DC + dc] = bf16_rne(tile[tx][ty + p * 8]);
    }
}

// -------------------------------------------------------------- bf16 MFMA GEMM
// C[M,N](bf16, stride OSTR) = A[MPAD,KPAD](bf16) @ B^T rows[NPAD,KPAD](bf16).
// grid = (N/128, M/128): blockIdx.x = n-block -> XCD pinning of B-slices,
// A streams once. 128x128 tile, BK=32, 4 waves of 64x64.
template <int KPAD>
__global__ __launch_bounds__(256) void gemm_mfma(const unsigned short* __restrict__ A,
                                                 const unsigned short* __restrict__ B,
                                                 unsigned short* __restrict__ C,
                                                 int M, int N, int OSTR) {
    __shared__ __align__(16) unsigned short sA[128 * 32];
    __shared__ __align__(16) unsigned short sB[128 * 32];
    const int t = threadIdx.x;
    const int w = t >> 6, lane = t & 63;
    const int m0 = blockIdx.y * 128, n0 = blockIdx.x * 128;
    const int wm = (w >> 1) * 64, wn = (w & 1) * 64;

    const int srow = lane >> 2;
    const int skc  = (lane & 3) * 8;
    const int mrow = lane & 15, quad = lane >> 4;

    f32x4 acc[4][4] = {};

    for (int k0 = 0; k0 < KPAD; k0 += 32) {
        #pragma unroll
        for (int c = 0; c < 2; ++c) {
            int rbase = c * 64 + w * 16;
            gl_lds16(A + (size_t)(m0 + rbase + srow) * KPAD + k0 + skc, &sA[rbase * 32]);
            gl_lds16(B + (size_t)(n0 + rbase + srow) * KPAD + k0 + skc, &sB[rbase * 32]);
        }
        __syncthreads();

        short8 af[4], bf[4];
        #pragma unroll
        for (int mt = 0; mt < 4; ++mt)
            af[mt] = *(const short8*)&sA[(wm + mt * 16 + mrow) * 32 + quad * 8];
        #pragma unroll
        for (int nt = 0; nt < 4; ++nt)
            bf[nt] = *(const short8*)&sB[(wn + nt * 16 + mrow) * 32 + quad * 8];
        #pragma unroll
        for (int mt = 0; mt < 4; ++mt)
            #pragma unroll
            for (int nt = 0; nt < 4; ++nt)
                acc[mt][nt] = __builtin_amdgcn_mfma_f32_16x16x32_bf16(
                    af[mt], bf[nt], acc[mt][nt], 0, 0, 0);
        __syncthreads();
    }

    // C/D layout: col = lane&15, row = quad*4 + reg
    #pragma unroll
    for (int mt = 0; mt < 4; ++mt) {
        int m = m0 + wm + mt * 16 + quad * 4;
        #pragma unroll
        for (int nt = 0; nt < 4; ++nt) {
            int n = n0 + wn + nt * 16 + mrow;
            if (n >= N) continue;
            #pragma unroll
            for (int r = 0; r < 4; ++r)
                if (m + r < M) C[(size_t)(m + r) * OSTR + n] = bf16_rne(acc[mt][nt][r]);
        }
    }
}

// -------------------------------- agg1: X1 = relu(agg(H1)+b1), bf16 -> bf16
// one 128-thread block per node; lanes 0..124 cover 1000 cols via ushort8;
// lanes 125..127 write the zero pad (cols 1000..1023) of X1.
__global__ __launch_bounds__(128) void agg1_bf16(const unsigned short* __restrict__ H,
                                                 const int* __restrict__ offs,
                                                 const int* __restrict__ srcs,
                                                 const float* __restrict__ bias,
                                                 unsigned short* __restrict__ X) {
    __shared__ int sl[128];
    const int i = blockIdx.x, t = threadIdx.x;
    const int beg = offs[i], end = offs[i + 1];
    const bool active = t < 125;
    float s[8] = {};
    for (int base = beg; base < end; base += 128) {
        int n = min(128, end - base);
        __syncthreads();
        if (t < n) sl[t] = srcs[base + t];
        __syncthreads();
        if (active) {
            for (int e = 0; e < n; ++e) {
                ushort8_t v = *(const ushort8_t*)(H + (size_t)sl[e] * H1STR + t * 8);
                #pragma unroll
                for (int u = 0; u < 8; ++u) s[u] += bf16_up(v[u]);
            }
        }
    }
    ushort8_t o = (ushort8_t)0;
    if (active) {
        #pragma unroll
        for (int u = 0; u < 8; ++u)
            o[u] = bf16_rne(fmaxf(s[u] + bias[t * 8 + u], 0.f));
    }
    *(ushort8_t*)(X + (size_t)i * K2PAD + t * 8) = o;
}

// ---------------- agg2 + layer3: out = relu(relu(agg(H2)+b2) @ W3 + b3)
// one 128-thread block per node; lanes 0..124 cover 500 cols via ushort4.
__global__ __launch_bounds__(128) void agg2_out(const unsigned short* __restrict__ H,
                                                const int* __restrict__ offs,
                                                const int* __restrict__ srcs,
                                                const float* __restrict__ b2,
                                                const float* __restrict__ W3,
                                                const float* __restrict__ b3,
                                                float* __restrict__ out) {
    __shared__ int sl[128];
    __shared__ float red[2][8];
    const int i = blockIdx.x, t = threadIdx.x;
    const int beg = offs[i], end = offs[i + 1];
    const bool active = t < 125;
    float s[4] = {};
    for (int base = beg; base < end; base += 128) {
        int n = min(128, end - base);
        __syncthreads();
        if (t < n) sl[t] = srcs[base + t];
        __syncthreads();
        if (active) {
            for (int e = 0; e < n; ++e) {
                ushort4 v = *(const ushort4*)(H + (size_t)sl[e] * H2STR + t * 4);
                s[0] += bf16_up(v.x); s[1] += bf16_up(v.y);
                s[2] += bf16_up(v.z); s[3] += bf16_up(v.w);
            }
        }
    }
    float acc[D_OUT] = {};
    if (active) {
        #pragma unroll
        for (int u = 0; u < 4; ++u) {
            float x = fmaxf(s[u] + b2[t * 4 + u], 0.f);
            const float* w = W3 + (size_t)(t * 4 + u) * D_OUT;
            #pragma unroll
            for (int j = 0; j < D_OUT; ++j) acc[j] += x * w[j];
        }
    }
    #pragma unroll
    for (int j = 0; j < D_OUT; ++j)
        #pragma unroll
        for (int off = 32; off; off >>= 1) acc[j] += __shfl_down(acc[j], off);
    const int lane = t & 63, wave = t >> 6;
    if (lane == 0) {
        #pragma unroll
        for (int j = 0; j < D_OUT; ++j) red[wave][j] = acc[j];
    }
    __syncthreads();
    if (t == 0) {
        #pragma unroll
        for (int j = 0; j < D_OUT; ++j)
            out[(size_t)i * D_OUT + j] = fmaxf(red[0][j] + red[1][j] + b3[j], 0.f);
    }
}

// ---------------------------------------------------------------------- launch
extern "C" void kernel_launch(void* const* d_in, const int* in_sizes, int n_in,
                              void* d_out, int out_size, void* d_ws, size_t ws_size,
                              hipStream_t stream) {
    const float* features = (const float*)d_in[0];
    const int*   src      = (const int*)d_in[1];
    const int*   dst      = (const int*)d_in[2];
    const float* W1       = (const float*)d_in[3];
    const float* b1       = (const float*)d_in[4];
    const float* W2       = (const float*)d_in[5];
    const float* b2       = (const float*)d_in[6];
    const float* W3       = (const float*)d_in[7];
    const float* b3       = (const float*)d_in[8];
    float* out = (float*)d_out;

    char* ws = (char*)d_ws;
    // X1bf overlays Fbf (GEMM1 done before agg1 writes); H2 overlays H1.
    unsigned short* Fbf  = (unsigned short*)(ws + 0);          // [MPAD][K1PAD]  57,876,480 B
    unsigned short* X1bf = (unsigned short*)(ws + 0);          // [MPAD][K2PAD]  41,156,608 B
    unsigned short* H1   = (unsigned short*)(ws + 57876480);   // [20000][H1STR] 40,320,000 B
    unsigned short* H2   = (unsigned short*)(ws + 57876480);   // [20000][H2STR] 20,160,000 B
    unsigned short* W1T  = (unsigned short*)(ws + 98196480);   // [N1PAD][K1PAD]  2,949,120 B
    unsigned short* W2T  = (unsigned short*)(ws + 101145600);  // [N2PAD][K2PAD]  1,048,576 B
    int* offs   = (int*)(ws + 102194176);                      // 20001 ints
    int* cursor = (int*)(ws + 102274304);
    int* srcs   = (int*)(ws + 102354432);                      // 200000 ints

    // ---- CSR build
    hipMemsetAsync(offs, 0, (N_NODES + 1) * sizeof(int), stream);
    count_deg<<<(N_EDGES + 255) / 256, 256, 0, stream>>>(dst, offs);
    scan_inclusive<<<1, 1024, 0, stream>>>(offs, N_NODES + 1);
    hipMemcpyAsync(cursor, offs, N_NODES * sizeof(int), hipMemcpyDeviceToDevice, stream);
    fill_csr<<<(N_EDGES + 255) / 256, 256, 0, stream>>>(src, dst, cursor, srcs);

    // ---- casts
    cast_features<<<MPAD, 256, 0, stream>>>(features, (unsigned int*)Fbf);
    transpose_cast_pad<D_IN, D_H1, N1PAD, K1PAD>
        <<<dim3(N1PAD / 32, K1PAD / 32), 256, 0, stream>>>(W1, W1T);
    transpose_cast_pad<D_H1, D_H2, N2PAD, K2PAD>
        <<<dim3(N2PAD / 32, K2PAD / 32), 256, 0, stream>>>(W2, W2T);

    // ---- layer 1: H1 = F @ W1 (bf16 out); X1 = relu(agg(H1)+b1) (bf16 padded)
    gemm_mfma<K1PAD><<<dim3(N1PAD / 128, MPAD / 128), 256, 0, stream>>>(
        Fbf, W1T, H1, N_NODES, D_H1, H1STR);
    // zero X1bf pad rows (20000..20095) before agg1/GEMM2 (stream-ordered after GEMM1)
    hipMemsetAsync(ws + (size_t)N_NODES * K2PAD * 2, 0,
                   (size_t)(MPAD - N_NODES) * K2PAD * 2, stream);
    agg1_bf16<<<N_NODES, 128, 0, stream>>>(H1, offs, srcs, b1, X1bf);

    // ---- layer 2: H2 = X1 @ W2 (bf16 out); out = fused agg2 + layer3
    gemm_mfma<K2PAD><<<dim3(N2PAD / 128, MPAD / 128), 256, 0, stream>>>(
        X1bf, W2T, H2, N_NODES, D_H2, H2STR);
    agg2_out<<<N_NODES, 128, 0, stream>>>(H2, offs, srcs, b2, W3, b3, out);
}